// Round 9
// baseline (915.770 us; speedup 1.0000x reference)
//
#include <hip/hip_runtime.h>

typedef __attribute__((ext_vector_type(8))) short short8;
typedef __attribute__((ext_vector_type(4))) short s16x4;
typedef __attribute__((ext_vector_type(4))) float f32x4;
typedef __attribute__((ext_vector_type(4))) unsigned int u32x4;

__device__ __forceinline__ ushort f2bf(float f){
  uint u = __float_as_uint(f);
  return (ushort)((u + 0x7fffu + ((u>>16)&1u)) >> 16);
}
__device__ __forceinline__ float bf2f(ushort h){ return __uint_as_float(((uint)h)<<16); }
__device__ __forceinline__ float gelu_f(float v){
  float u = v*(0.7978845608f + 0.0356774081f*v*v);
  float e = __expf(2.f*u);
  float th = 1.f - 2.f/(e+1.f);
  return 0.5f*v*(1.f+th);
}
__device__ __forceinline__ uint pk2(float a, float b){
  return (uint)f2bf(a) | ((uint)f2bf(b)<<16);
}

#define MFMA(a,b,c) __builtin_amdgcn_mfma_f32_16x16x32_bf16(a,b,c,0,0,0)
#define LDS_FENCE() do{ asm volatile("s_waitcnt lgkmcnt(0)" ::: "memory"); __builtin_amdgcn_sched_barrier(0); }while(0)

// ---------------- K0: convert + transpose weights to bf16 [N][K] ----------------
__global__ __launch_bounds__(256) void k_convert_w(
    const float* __restrict__ wq, const float* __restrict__ wp,
    const float* __restrict__ sq, const float* __restrict__ sp,
    const float* __restrict__ m1, const float* __restrict__ m2,
    ushort* __restrict__ dst)
{
  int i = blockIdx.x*256 + threadIdx.x;   // total 262144
  const float* src; int N, base, kb;
  if      (i < 49152)  { src=wq; N=384; base=0;      kb=7; }
  else if (i < 65536)  { src=wp; N=128; base=49152;  kb=7; }
  else if (i < 114688) { src=sq; N=384; base=65536;  kb=7; }
  else if (i < 131072) { src=sp; N=128; base=114688; kb=7; }
  else if (i < 196608) { src=m1; N=512; base=131072; kb=7; }
  else                 { src=m2; N=128; base=196608; kb=9; }
  int o = i - base;
  int n = o >> kb;
  int k = o & ((1<<kb)-1);
  dst[i] = f2bf(src[(size_t)k*N + n]);
}

// ---------------- K1: x (B,C,H,W) -> y=(B,HW,C) f32 ; xl = LN(y) bf16 ----------------
__global__ __launch_bounds__(256) void k_transpose_ln(
    const float* __restrict__ x, const float* __restrict__ g, const float* __restrict__ b,
    float* __restrict__ y, ushort* __restrict__ xl)
{
  __shared__ float tile[64][133];
  int bh = blockIdx.x, bb = bh>>6, h = bh&63;
  const float* xp = x + (size_t)bb*524288 + (size_t)h*64;
  for (int i = threadIdx.x; i < 8192; i += 256){
    int c = i>>6, w = i&63;
    tile[w][c] = xp[(size_t)c*4096 + w];
  }
  __syncthreads();
  int w = threadIdx.x>>2, q = threadIdx.x&3;
  float s=0.f, ss=0.f;
  #pragma unroll
  for (int cc=0; cc<32; cc++){ float v = tile[w][q*32+cc]; s+=v; ss+=v*v; }
  s  += __shfl_xor(s,1);  s  += __shfl_xor(s,2);
  ss += __shfl_xor(ss,1); ss += __shfl_xor(ss,2);
  float mu = s*0.0078125f;
  float rstd = rsqrtf(ss*0.0078125f - mu*mu + 1e-5f);
  size_t row = ((size_t)bb*4096 + h*64 + w)*128;
  float* yp = y + row; ushort* xp2 = xl + row;
  #pragma unroll
  for (int cc=0; cc<32; cc+=4){
    int c = q*32+cc;
    f32x4 v = { tile[w][c], tile[w][c+1], tile[w][c+2], tile[w][c+3] };
    *(f32x4*)(yp+c) = v;
  }
  #pragma unroll
  for (int cc=0; cc<32; cc+=8){
    int c0 = q*32+cc;
    short8 hv;
    #pragma unroll
    for (int z=0; z<8; z++){
      int c = c0+z;
      hv[z] = (short)f2bf((tile[w][c]-mu)*rstd*g[c] + b[c]);
    }
    *(short8*)(xp2 + c0) = hv;
  }
}

// ---------------- K2: full transformer block, barrier-free, wave-local ----------------
// grid 2048 = (b:32) x (wh:32) x (half:2). 4 waves; wave owns 4 complete 2x2 windows
// = 16 tokens. All phases wave-local; no __syncthreads.
template<bool SHIFT, bool FINAL>
__global__ __launch_bounds__(256,3) void k_block(
    const ushort* __restrict__ xlin, const float* __restrict__ yin,
    float* __restrict__ yout, ushort* __restrict__ xlout,
    const ushort* __restrict__ wqT, const float* __restrict__ qb,
    const ushort* __restrict__ wpT, const float* __restrict__ pb,
    const ushort* __restrict__ w1T, const float* __restrict__ b1,
    const ushort* __restrict__ w2T, const float* __restrict__ b2,
    const float* __restrict__ pos, const float* __restrict__ g,
    const float* __restrict__ bvec)
{
  __shared__ __align__(16) ushort lds[24576];   // 48KB: 4 waves x (Q 4KB | K 4KB | V 4KB)
  const f32x4 zf4 = {0.f,0.f,0.f,0.f};
  const int t = threadIdx.x, lane = t&63, wave = t>>6, lr = lane&15, hi = lane>>4;
  ushort* QS = lds + wave*6144;   // [4h][16t][32e]; later O tile [16t][128c] swizzled
  ushort* KS = QS + 2048;         // [4h][16t][32e]; later xl' tile [16t][128c] swizzled
  ushort* VS = QS + 4096;         // [4h][32e][16t] chunk-swizzled
  const int bb = blockIdx.x>>6, rem = blockIdx.x&63;
  const int wh = rem>>1, wha = rem&1, c0 = wha*32;
  const int wl_lr = lr>>2, il = lr&3, xi = il>>1, yi = il&1;
  const int oh = 2*wh + xi, ow = c0 + (wave*4 + wl_lr)*2 + yi;
  const int ih = SHIFT ? ((oh+1)&63) : oh, iw = SHIFT ? ((ow+1)&63) : ow;
  // ---- xl A-fragments (rows = this wave's 16 tokens) ----
  const ushort* xrow = xlin + ((long)bb*4096 + ih*64 + iw)*128;
  short8 aq[4];
  #pragma unroll
  for (int kx=0;kx<4;kx++) aq[kx] = *(const short8*)(xrow + kx*32 + hi*8);
  // ---- QKV GEMM: D[token 4hi+r2][n 16nt+lr], scatter to Q/K/V LDS ----
  {
    short8 wf[4], wfn[4];
    #pragma unroll
    for (int kx=0;kx<4;kx++) wf[kx] = *(const short8*)(wqT + (long)lr*128 + kx*32 + hi*8);
    for (int nt=0; nt<24; nt++){
      if (nt<23){
        #pragma unroll
        for (int kx=0;kx<4;kx++) wfn[kx] = *(const short8*)(wqT + (long)((nt+1)*16+lr)*128 + kx*32 + hi*8);
      }
      f32x4 acc = zf4;
      #pragma unroll
      for (int kx=0;kx<4;kx++) acc = MFMA(aq[kx], wf[kx], acc);
      int n = nt*16 + lr;
      float bv = qb[n];
      int cc2 = n/3, which = n - cc2*3;
      int h = cc2&3, e = cc2>>2;
      #pragma unroll
      for (int r2=0;r2<4;r2++){
        ushort us = f2bf(acc[r2]+bv);
        if (which==2) VS[(h*32+e)*16 + ((hi^((e>>2)&3))<<2) + r2] = us;
        else { ushort* dst = which ? KS : QS; dst[(h*16+4*hi+r2)*32 + e] = us; }
      }
      if (nt<23){
        #pragma unroll
        for (int kx=0;kx<4;kx++) wf[kx]=wfn[kx];
      }
    }
  }
  LDS_FENCE();
  // ---- attention per head: S^T = mfma(K,Q); per-lane softmax; PV = mfma(P,V^T) ----
  float posv[4];
  #pragma unroll
  for (int r2=0;r2<4;r2++) posv[r2] = pos[((r2>>1)-xi+1)*3 + (r2&1)-yi+1];
  const bool wh31 = SHIFT && (wh==31);
  const bool ww31 = SHIFT && (wha==1) && (wave==3) && (wl_lr==3);
  const int vsw = (lr>>2)&3;
  const int psrc = (wl_lr<<4) | lr;                    // softmax-owner lane for row i=lr
  const bool supA = (hi == (wl_lr>>1)) && ((wl_lr&1)==0);
  const bool supB = (hi == (wl_lr>>1)) && ((wl_lr&1)==1);
  f32x4 of[4][2];
  #pragma unroll
  for (int h=0;h<4;h++){
    short8 kf = *(const short8*)(KS + (h*16+lr)*32 + hi*8);
    short8 qf = *(const short8*)(QS + (h*16+lr)*32 + hi*8);
    f32x4 st = MFMA(kf, qf, zf4);  // D[j=4hi+r2][i=lr]
    float s[4];
    #pragma unroll
    for (int r2=0;r2<4;r2++){
      float v = st[r2]*0.17677669529663687f + posv[r2];
      if (SHIFT){
        if (wh31 && (xi != (r2>>1))) v = -1e30f;
        if (ww31 && (yi != (r2&1))) v = -1e30f;
      }
      s[r2] = v;
    }
    float mx = fmaxf(fmaxf(s[0],s[1]), fmaxf(s[2],s[3]));
    float p0=__expf(s[0]-mx), p1=__expf(s[1]-mx), p2=__expf(s[2]-mx), p3=__expf(s[3]-mx);
    float inv = 1.f/(p0+p1+p2+p3);
    uint pw0 = pk2(p0*inv, p1*inv), pw1 = pk2(p2*inv, p3*inv);
    uint qw0 = (uint)__shfl((int)pw0, psrc);
    uint qw1 = (uint)__shfl((int)pw1, psrc);
    union { u32x4 u; short8 s8; } afu;
    afu.u = (u32x4){ supA?qw0:0u, supA?qw1:0u, supB?qw0:0u, supB?qw1:0u };
    #pragma unroll
    for (int half=0; half<2; half++){
      int e = lr + 16*half;
      const ushort* vbase = VS + (h*32+e)*16;
      // &3 clamp: lanes hi>=2 supply k=16..31 whose A-rows are zero; clamping keeps
      // the (multiplied-by-zero) B reads inside the valid finite 16-token row.
      // Without it, reads run past the 48KB allocation -> junk bits -> 0*Inf = NaN.
      s16x4 ca = *(const s16x4*)(vbase + ((((2*hi  )^vsw)&3)<<2));
      s16x4 cb = *(const s16x4*)(vbase + ((((2*hi+1)^vsw)&3)<<2));
      short8 vb = { ca[0],ca[1],ca[2],ca[3], cb[0],cb[1],cb[2],cb[3] };
      of[h][half] = MFMA(afu.s8, vb, zf4);   // D[i=4hi+r2][e]
    }
  }
  // ---- write O tile [16t][128c], chunk-XOR swizzled, into QS ----
  #pragma unroll
  for (int h=0;h<4;h++)
    #pragma unroll
    for (int half=0;half<2;half++)
      #pragma unroll
      for (int r2=0;r2<4;r2++){
        int tk = 4*hi + r2, c = h*32 + 16*half + lr;
        QS[tk*128 + ((((c>>3)^tk)&15)<<3) + (c&7)] = f2bf(of[h][half][r2]);
      }
  LDS_FENCE();
  // ---- proj GEMM + bias + residual + LN -> xl' (LDS only) ----
  long yrow[4];
  #pragma unroll
  for (int r2=0;r2<4;r2++){
    int tk = 4*hi + r2, ilk = tk&3;
    int oh2 = 2*wh + (ilk>>1), ow2 = c0 + (wave*4 + (tk>>2))*2 + (ilk&1);
    yrow[r2] = ((long)bb*4096 + oh2*64 + ow2)*128;
  }
  f32x4 yv[8];
  {
    short8 ao[4];
    #pragma unroll
    for (int kx=0;kx<4;kx++)
      ao[kx] = *(const short8*)(QS + lr*128 + ((((4*kx+hi)^lr)&15)<<3));
    #pragma unroll
    for (int nt=0;nt<8;nt++){
      f32x4 acc = zf4;
      #pragma unroll
      for (int kx=0;kx<4;kx++){
        short8 bw = *(const short8*)(wpT + (long)(nt*16+lr)*128 + kx*32 + hi*8);
        acc = MFMA(ao[kx], bw, acc);
      }
      yv[nt] = acc;
    }
  }
  {
    float sum[4]={0,0,0,0}, sq[4]={0,0,0,0};
    #pragma unroll
    for (int nt=0;nt<8;nt++){
      int col = nt*16+lr;
      float bv = pb[col];
      #pragma unroll
      for (int r2=0;r2<4;r2++){
        float v = yv[nt][r2] + bv + yin[yrow[r2]+col];
        yv[nt][r2] = v;
        sum[r2]+=v; sq[r2]+=v*v;
      }
    }
    #pragma unroll
    for (int r2=0;r2<4;r2++){
      float a=sum[r2], b2s=sq[r2];
      #pragma unroll
      for (int o2=1;o2<16;o2<<=1){ a+=__shfl_xor(a,o2); b2s+=__shfl_xor(b2s,o2); }
      sum[r2]=a; sq[r2]=b2s;
    }
    #pragma unroll
    for (int r2=0;r2<4;r2++){
      float mu = sum[r2]*0.0078125f;
      float rstd = rsqrtf(sq[r2]*0.0078125f - mu*mu + 1e-5f);
      int tk = 4*hi + r2;
      #pragma unroll
      for (int nt=0;nt<8;nt++){
        int col = nt*16+lr;
        float xv = (yv[nt][r2]-mu)*rstd*g[col] + bvec[col];
        KS[tk*128 + ((((col>>3)^tk)&15)<<3) + (col&7)] = f2bf(xv);
      }
    }
  }
  LDS_FENCE();
  // ---- MLP: h = gelu(xl'@W1^T) kept in regs (swapped), MLP2 via shfl-assembled frags ----
  f32x4 acc2[8];
  #pragma unroll
  for (int nt=0;nt<8;nt++) acc2[nt] = zf4;
  short8 bx[4];
  #pragma unroll
  for (int kx=0;kx<4;kx++)
    bx[kx] = *(const short8*)(KS + lr*128 + ((((4*kx+hi)^lr)&15)<<3));
  #pragma unroll 1
  for (int qq=0; qq<4; qq++){
    uint hp[8][2];
    #pragma unroll
    for (int nt2=0;nt2<8;nt2++){
      f32x4 hacc = zf4;
      #pragma unroll
      for (int kx=0;kx<4;kx++){
        short8 wf = *(const short8*)(w1T + (long)(qq*128 + nt2*16 + lr)*128 + kx*32 + hi*8);
        hacc = MFMA(wf, bx[kx], hacc);       // D[n1=4hi+r2][tok=lr]
      }
      f32x4 vb = *(const f32x4*)(b1 + qq*128 + nt2*16 + 4*hi);
      hp[nt2][0] = pk2(gelu_f(hacc[0]+vb[0]), gelu_f(hacc[1]+vb[1]));
      hp[nt2][1] = pk2(gelu_f(hacc[2]+vb[2]), gelu_f(hacc[3]+vb[3]));
    }
    const int srcA = (((2*hi  )&3)<<4) | lr;
    const int srcB = (((2*hi+1)&3)<<4) | lr;
    const bool hup = hi>=2;
    #pragma unroll
    for (int kcl=0;kcl<4;kcl++){
      uint a0 = (uint)__shfl((int)hp[2*kcl  ][0], srcA);
      uint a1 = (uint)__shfl((int)hp[2*kcl  ][1], srcA);
      uint a2 = (uint)__shfl((int)hp[2*kcl+1][0], srcA);
      uint a3 = (uint)__shfl((int)hp[2*kcl+1][1], srcA);
      uint b0 = (uint)__shfl((int)hp[2*kcl  ][0], srcB);
      uint b1w= (uint)__shfl((int)hp[2*kcl  ][1], srcB);
      uint b2w= (uint)__shfl((int)hp[2*kcl+1][0], srcB);
      uint b3 = (uint)__shfl((int)hp[2*kcl+1][1], srcB);
      union { u32x4 u; short8 s8; } afm;
      afm.u = (u32x4){ hup?a2:a0, hup?a3:a1, hup?b2w:b0, hup?b3:b1w };
      #pragma unroll
      for (int nt2=0;nt2<8;nt2++){
        short8 w2f = *(const short8*)(w2T + (long)(nt2*16+lr)*512 + qq*128 + kcl*32 + hi*8);
        acc2[nt2] = MFMA(afm.s8, w2f, acc2[nt2]);   // D[tok=4hi+r2][n2=16nt2+lr]
      }
    }
  }
  // ---- final epilogue: y = y_mid + mlp + b2 ; (LN -> xlout) ----
  {
    float sum[4]={0,0,0,0}, sq[4]={0,0,0,0};
    #pragma unroll
    for (int nt=0;nt<8;nt++){
      int col = nt*16+lr;
      float bv = b2[col];
      #pragma unroll
      for (int r2=0;r2<4;r2++){
        float v = yv[nt][r2] + acc2[nt][r2] + bv;
        acc2[nt][r2] = v;
        sum[r2]+=v; sq[r2]+=v*v;
      }
    }
    if (!FINAL){
      #pragma unroll
      for (int r2=0;r2<4;r2++){
        float a=sum[r2], b2s=sq[r2];
        #pragma unroll
        for (int o2=1;o2<16;o2<<=1){ a+=__shfl_xor(a,o2); b2s+=__shfl_xor(b2s,o2); }
        sum[r2]=a; sq[r2]=b2s;
      }
    }
    #pragma unroll
    for (int r2=0;r2<4;r2++){
      float mu = sum[r2]*0.0078125f;
      float rstd = rsqrtf(sq[r2]*0.0078125f - mu*mu + 1e-5f);
      #pragma unroll
      for (int nt=0;nt<8;nt++){
        int col = nt*16+lr;
        float v = acc2[nt][r2];
        yout[yrow[r2]+col] = v;
        if (!FINAL) xlout[yrow[r2]+col] = f2bf((v-mu)*rstd*g[col] + bvec[col]);
      }
    }
  }
}

// ---------------- launch ----------------
extern "C" void kernel_launch(void* const* d_in, const int* in_sizes, int n_in,
                              void* d_out, int out_size, void* d_ws, size_t ws_size,
                              hipStream_t stream)
{
  const float* x    = (const float*)d_in[0];
  const float* ln_g = (const float*)d_in[1];
  const float* ln_b = (const float*)d_in[2];
  const float* wq_W = (const float*)d_in[3];
  const float* wq_b = (const float*)d_in[4];
  const float* wp_W = (const float*)d_in[5];
  const float* wp_b = (const float*)d_in[6];
  const float* wpos = (const float*)d_in[7];
  const float* sq_W = (const float*)d_in[8];
  const float* sq_b = (const float*)d_in[9];
  const float* sp_W = (const float*)d_in[10];
  const float* sp_b = (const float*)d_in[11];
  const float* spos = (const float*)d_in[12];
  const float* m1_W = (const float*)d_in[13];
  const float* m1_b = (const float*)d_in[14];
  const float* m2_W = (const float*)d_in[15];
  const float* m2_b = (const float*)d_in[16];

  float* y = (float*)d_out;                          // residual stream lives in d_out
  char* ws = (char*)d_ws;
  ushort* xl0 = (ushort*)ws;                               // 32 MB
  ushort* xl1 = (ushort*)(ws + (size_t)32*1024*1024);      // 32 MB
  ushort* wts = (ushort*)(ws + (size_t)64*1024*1024);      // 512 KB
  ushort* wqT = wts,          *wpT = wts + 49152,  *sqT = wts + 65536;
  ushort* spT = wts + 114688, *m1T = wts + 131072, *m2T = wts + 196608;

  k_convert_w<<<1024,256,0,stream>>>(wq_W,wp_W,sq_W,sp_W,m1_W,m2_W,wts);
  k_transpose_ln<<<2048,256,0,stream>>>(x, ln_g, ln_b, y, xl0);
  k_block<false,false><<<2048,256,0,stream>>>(xl0, y, y, xl1,
      wqT, wq_b, wpT, wp_b, m1T, m1_b, m2T, m2_b, wpos, ln_g, ln_b);
  k_block<true,true><<<2048,256,0,stream>>>(xl1, y, y, nullptr,
      sqT, sq_b, spT, sp_b, m1T, m1_b, m2T, m2_b, spos, ln_g, ln_b);
}